// Round 1
// baseline (905.555 us; speedup 1.0000x reference)
//
#include <hip/hip_runtime.h>

constexpr int NN = 100000;
constexpr int NE = 3200000;
constexpr int DD = 128;
#define BN_EPS 1e-5f

// ---- workspace layout (bytes) ----
constexpr size_t WS_DEG   = 0;          // int[NN]
constexpr size_t WS_OFF   = 400000;     // int[NN]
constexpr size_t WS_CUR   = 800000;     // int[NN]
constexpr size_t WS_TOTAL = 1200000;    // int[1]
constexpr size_t WS_FLAG  = 1200016;    // int[1] (1 if edge_index is int64)
constexpr size_t WS_BNSUM = 1200256;    // float[128]
constexpr size_t WS_BNSQ  = 1200768;    // float[128]
constexpr size_t WS_ZERO  = 1201280;    // memset range covers all of the above
constexpr size_t WS_CSR   = 1310720;    // int[NE]

// Detect whether edge_index arrived as int64 (viewed as int32 pairs: odd words all 0,
// since values are in [0, 100000) ). One wave.
__global__ void k_detect(const int* __restrict__ ei, int* __restrict__ flag) {
    int lane = threadIdx.x;
    int v = ei[2 * lane + 1];
    unsigned long long b = __ballot(v == 0);
    if (lane == 0) *flag = (b == ~0ull) ? 1 : 0;
}

__global__ __launch_bounds__(256) void k_deg(const int* __restrict__ ei,
                                             int* __restrict__ deg,
                                             const int* __restrict__ flag) {
    int e = blockIdx.x * 256 + threadIdx.x;
    if (e >= NE) return;
    int i64 = *flag;
    int dst = i64 ? ei[2 * (NE + e)] : ei[NE + e];
    atomicAdd(&deg[dst], 1);
}

__global__ __launch_bounds__(256) void k_off(const int* __restrict__ deg,
                                             int* __restrict__ off,
                                             int* __restrict__ cur,
                                             int* __restrict__ total) {
    int n = blockIdx.x * 256 + threadIdx.x;
    if (n >= NN) return;
    int d = deg[n];
    int o = atomicAdd(total, d);
    off[n] = o;
    cur[n] = o;
}

__global__ __launch_bounds__(256) void k_fill(const int* __restrict__ ei,
                                              int* __restrict__ cur,
                                              int* __restrict__ csr,
                                              const int* __restrict__ flag) {
    int e = blockIdx.x * 256 + threadIdx.x;
    if (e >= NE) return;
    int i64 = *flag;
    int src = i64 ? ei[2 * e] : ei[e];
    int dst = i64 ? ei[2 * (NE + e)] : ei[NE + e];
    int p = atomicAdd(&cur[dst], 1);
    csr[p] = src;
}

// One wave (64 lanes) per node; each lane owns 2 features (float2). Gather-sum
// over the node's CSR bucket, then divide by max(deg,1).
__global__ __launch_bounds__(256) void k_agg(const float* __restrict__ x,
                                             const int* __restrict__ csr,
                                             const int* __restrict__ deg,
                                             const int* __restrict__ off,
                                             float* __restrict__ agg) {
    int w = (blockIdx.x * 256 + threadIdx.x) >> 6;
    int lane = threadIdx.x & 63;
    if (w >= NN) return;
    int dg = deg[w];
    int o = off[w];
    const float2* x2 = (const float2*)x;
    float ax = 0.f, ay = 0.f;
    int j = 0;
    for (; j + 1 < dg; j += 2) {
        int s0 = csr[o + j];
        int s1 = csr[o + j + 1];
        float2 v0 = x2[(size_t)s0 * 64 + lane];
        float2 v1 = x2[(size_t)s1 * 64 + lane];
        ax += v0.x + v1.x;
        ay += v0.y + v1.y;
    }
    if (j < dg) {
        int s = csr[o + j];
        float2 v = x2[(size_t)s * 64 + lane];
        ax += v.x;
        ay += v.y;
    }
    float inv = 1.0f / fmaxf((float)dg, 1.0f);
    float2 r;
    r.x = ax * inv;
    r.y = ay * inv;
    ((float2*)agg)[(size_t)w * 64 + lane] = r;
}

// x_raw = agg @ W_l + b_l + x @ W_r.  Block: 256 threads -> 32 rows x 128 cols.
// Thread: 4 rows x 4 cols. W staged in 64KB LDS, two passes (acc persists).
__global__ __launch_bounds__(256) void k_gemm(const float* __restrict__ agg,
                                              const float* __restrict__ x,
                                              const float* __restrict__ Wl,
                                              const float* __restrict__ Wr,
                                              const float* __restrict__ bl,
                                              float* __restrict__ out_raw) {
    extern __shared__ float sW[];  // 128*128 floats = 64KB
    int tid = threadIdx.x;
    int cg = tid & 31;
    int rg = tid >> 5;
    int c0 = cg * 4;
    int row0 = blockIdx.x * 32 + rg * 4;

    float acc[4][4] = {};

    #pragma unroll
    for (int m = 0; m < 2; ++m) {
        const float* Wsrc = (m == 0) ? Wl : Wr;
        const float* src  = (m == 0) ? agg : x;
        __syncthreads();  // protect LDS before overwrite (second pass)
        {
            const float4* W4 = (const float4*)Wsrc;
            float4* sW4 = (float4*)sW;
            for (int i = tid; i < DD * DD / 4; i += 256) sW4[i] = W4[i];
        }
        __syncthreads();
        for (int k = 0; k < DD; k += 4) {
            float w[4][4];
            #pragma unroll
            for (int kk = 0; kk < 4; ++kk) {
                float4 t = *(const float4*)&sW[(k + kk) * DD + c0];
                w[kk][0] = t.x; w[kk][1] = t.y; w[kk][2] = t.z; w[kk][3] = t.w;
            }
            #pragma unroll
            for (int r = 0; r < 4; ++r) {
                float4 t = *(const float4*)&src[(size_t)(row0 + r) * DD + k];
                float a0 = t.x, a1 = t.y, a2 = t.z, a3 = t.w;
                #pragma unroll
                for (int c = 0; c < 4; ++c)
                    acc[r][c] += a0 * w[0][c] + a1 * w[1][c] + a2 * w[2][c] + a3 * w[3][c];
            }
        }
    }

    float4 b4 = *(const float4*)&bl[c0];
    #pragma unroll
    for (int r = 0; r < 4; ++r) {
        float4 o;
        o.x = acc[r][0] + b4.x;
        o.y = acc[r][1] + b4.y;
        o.z = acc[r][2] + b4.z;
        o.w = acc[r][3] + b4.w;
        *(float4*)&out_raw[(size_t)(row0 + r) * DD + c0] = o;
    }
}

// Column sums + sumsq over 100000 rows. 512 blocks, block-LDS reduce, then
// one atomicAdd per column per block.
__global__ __launch_bounds__(256) void k_stats(const float* __restrict__ raw,
                                               float* __restrict__ bn_sum,
                                               float* __restrict__ bn_sq) {
    __shared__ float s_s[8][128];
    __shared__ float s_q[8][128];
    int cg = threadIdx.x & 31;
    int rg = threadIdx.x >> 5;
    int c0 = cg * 4;
    float s0 = 0, s1 = 0, s2 = 0, s3 = 0;
    float q0 = 0, q1 = 0, q2 = 0, q3 = 0;
    for (int r = blockIdx.x * 8 + rg; r < NN; r += gridDim.x * 8) {
        float4 v = *(const float4*)&raw[(size_t)r * DD + c0];
        s0 += v.x; q0 += v.x * v.x;
        s1 += v.y; q1 += v.y * v.y;
        s2 += v.z; q2 += v.z * v.z;
        s3 += v.w; q3 += v.w * v.w;
    }
    s_s[rg][c0 + 0] = s0; s_s[rg][c0 + 1] = s1; s_s[rg][c0 + 2] = s2; s_s[rg][c0 + 3] = s3;
    s_q[rg][c0 + 0] = q0; s_q[rg][c0 + 1] = q1; s_q[rg][c0 + 2] = q2; s_q[rg][c0 + 3] = q3;
    __syncthreads();
    if (threadIdx.x < 128) {
        float ts = 0, tq = 0;
        #pragma unroll
        for (int g = 0; g < 8; ++g) {
            ts += s_s[g][threadIdx.x];
            tq += s_q[g][threadIdx.x];
        }
        atomicAdd(&bn_sum[threadIdx.x], ts);
        atomicAdd(&bn_sq[threadIdx.x], tq);
    }
}

__global__ __launch_bounds__(256) void k_norm(const float* __restrict__ raw,
                                              const float* __restrict__ bn_sum,
                                              const float* __restrict__ bn_sq,
                                              const float* __restrict__ gamma,
                                              const float* __restrict__ beta,
                                              float* __restrict__ out) {
    const float invN = 1.0f / (float)NN;
    int total = NN * DD / 4;
    for (int idx = blockIdx.x * 256 + threadIdx.x; idx < total; idx += gridDim.x * 256) {
        int cp = idx & 31;  // column pack (4 cols)
        float4 v = ((const float4*)raw)[idx];
        float4 s = ((const float4*)bn_sum)[cp];
        float4 q = ((const float4*)bn_sq)[cp];
        float4 g = ((const float4*)gamma)[cp];
        float4 b = ((const float4*)beta)[cp];
        float4 o;
        {
            float mu = s.x * invN; float var = q.x * invN - mu * mu;
            o.x = (v.x - mu) * rsqrtf(var + BN_EPS) * g.x + b.x;
        }
        {
            float mu = s.y * invN; float var = q.y * invN - mu * mu;
            o.y = (v.y - mu) * rsqrtf(var + BN_EPS) * g.y + b.y;
        }
        {
            float mu = s.z * invN; float var = q.z * invN - mu * mu;
            o.z = (v.z - mu) * rsqrtf(var + BN_EPS) * g.z + b.z;
        }
        {
            float mu = s.w * invN; float var = q.w * invN - mu * mu;
            o.w = (v.w - mu) * rsqrtf(var + BN_EPS) * g.w + b.w;
        }
        ((float4*)out)[idx] = o;
    }
}

extern "C" void kernel_launch(void* const* d_in, const int* in_sizes, int n_in,
                              void* d_out, int out_size, void* d_ws, size_t ws_size,
                              hipStream_t stream) {
    const float* x     = (const float*)d_in[0];
    const int*   ei    = (const int*)d_in[1];
    const float* Wl    = (const float*)d_in[2];
    const float* bl    = (const float*)d_in[3];
    const float* Wr    = (const float*)d_in[4];
    const float* gamma = (const float*)d_in[5];
    const float* beta  = (const float*)d_in[6];

    float* out_raw = (float*)d_out;                       // [NN][DD] x_raw
    float* out_bn  = out_raw + (size_t)NN * DD;           // [NN][DD] x_deskewed (also temp agg)

    char* ws = (char*)d_ws;
    int*   deg    = (int*)(ws + WS_DEG);
    int*   off    = (int*)(ws + WS_OFF);
    int*   cur    = (int*)(ws + WS_CUR);
    int*   total  = (int*)(ws + WS_TOTAL);
    int*   flag   = (int*)(ws + WS_FLAG);
    float* bn_sum = (float*)(ws + WS_BNSUM);
    float* bn_sq  = (float*)(ws + WS_BNSQ);
    int*   csr    = (int*)(ws + WS_CSR);

    hipMemsetAsync(d_ws, 0, WS_ZERO, stream);

    k_detect<<<1, 64, 0, stream>>>(ei, flag);
    k_deg<<<(NE + 255) / 256, 256, 0, stream>>>(ei, deg, flag);
    k_off<<<(NN + 255) / 256, 256, 0, stream>>>(deg, off, cur, total);
    k_fill<<<(NE + 255) / 256, 256, 0, stream>>>(ei, cur, csr, flag);
    k_agg<<<(NN * 64 + 255) / 256, 256, 0, stream>>>(x, csr, deg, off, out_bn);
    k_gemm<<<NN / 32, 256, DD * DD * sizeof(float), stream>>>(out_bn, x, Wl, Wr, bl, out_raw);
    k_stats<<<512, 256, 0, stream>>>(out_raw, bn_sum, bn_sq);
    k_norm<<<4096, 256, 0, stream>>>(out_raw, bn_sum, bn_sq, gamma, beta, out_bn);
}